// Round 9
// baseline (119.191 us; speedup 1.0000x reference)
//
#include <hip/hip_runtime.h>

#define PNUM 128
#define BATCH 8192
#define WPB 4                      // waves per block, 1 batch per wave
#define GRID1 (BATCH / WPB)        // 2048 blocks of 256 threads

typedef _Float16 h2 __attribute__((ext_vector_type(2)));
typedef _Float16 h4 __attribute__((ext_vector_type(4)));
typedef _Float16 h8 __attribute__((ext_vector_type(8)));

// f32x2 -> f16x2 (RTZ), bit-cast around clang's __fp16/_Float16 vec mismatch
__device__ __forceinline__ h2 cvt2(float x, float y) {
    return __builtin_bit_cast(h2, __builtin_amdgcn_cvt_pkrtz(x, y));
}

// Packed smooth-L1 term, both coords, f32-accumulated. 5 guaranteed-packed ops:
// v_pk_add (d=p-q), v_and_b32 (a=|d|), v_pk_min (m=min(a,1)),
// v_pk_fma (t = a - 0.5m), v_dot2_f32_f16 (acc += m.t)
__device__ __forceinline__ void unit(h2 p, h2 q, float& acc) {
    h2 d = p - q;
    h2 a = __builtin_bit_cast(h2, __builtin_bit_cast(unsigned, d) & 0x7fff7fffu);
    h2 m = __builtin_elementwise_min(a, (h2)(_Float16)1.0f);
    h2 t = __builtin_elementwise_fma(m, (h2)(_Float16)-0.5f, a);
    acc = __builtin_amdgcn_fdot2(m, t, acc, false);
}

__device__ __forceinline__ h2 lo2(h4 v) { return __builtin_shufflevector(v, v, 0, 1); }
__device__ __forceinline__ h2 hi2(h4 v) { return __builtin_shufflevector(v, v, 2, 3); }

// One WAVE per batch, both preds. Lane k owns shifts {2k,2k+1}.
// gt ring (doubled, f16) + pred rows in per-wave LDS; per hh (4 j):
// 2x ds_read_b64 lane-sliding gather + 2x b128 wave-uniform broadcast.
// launch_bounds(,4): VGPR cap ~128 so unroll-8 lookahead can live in regs.
__global__ __launch_bounds__(64 * WPB, 4) void match_fused(
        const float* __restrict__ pred0,
        const float* __restrict__ pred1,
        const float* __restrict__ gt,
        float* __restrict__ out) {
    __shared__ __align__(16) _Float16 lds[WPB][1024];  // ring 512 | p0 256 | p1 256

    const int t = threadIdx.x;
    const int k = t & 63;
    const int w = __builtin_amdgcn_readfirstlane(t >> 6);
    const int b = blockIdx.x * WPB + w;

    _Float16* base = lds[w];
    h4* ring4 = (h4*)base;               // 128 entries = 256 points (doubled)
    h4* q0 = (h4*)(base + 512);          // 64 entries = 128 points
    h4* q1 = (h4*)(base + 768);

    // ---- stage + f32->f16 convert (own wave's region; no barrier needed) ----
    const float4* gv4 = (const float4*)(gt    + (size_t)b * (PNUM * 2));
    const float4* p0v = (const float4*)(pred0 + (size_t)b * (PNUM * 2));
    const float4* p1v = (const float4*)(pred1 + (size_t)b * (PNUM * 2));
    {
        float4 g = gv4[k];
        h2 c0 = cvt2(g.x, g.y);
        h2 c1 = cvt2(g.z, g.w);
        h4 gh = {c0.x, c0.y, c1.x, c1.y};
        ring4[k] = gh; ring4[k + 64] = gh;
        float4 p = p0v[k];
        c0 = cvt2(p.x, p.y);
        c1 = cvt2(p.z, p.w);
        q0[k] = (h4){c0.x, c0.y, c1.x, c1.y};
        p = p1v[k];
        c0 = cvt2(p.x, p.y);
        c1 = cvt2(p.z, p.w);
        q1[k] = (h4){c0.x, c0.y, c1.x, c1.y};
    }

    const h8* q0_8 = (const h8*)q0;      // 32 entries, wave-uniform broadcasts
    const h8* q1_8 = (const h8*)q1;

    h4 W = ring4[k];                     // points {2k, 2k+1}
    float a00 = 0.f, a01 = 0.f, a10 = 0.f, a11 = 0.f;

#pragma unroll 8
    for (int hh = 0; hh < 32; ++hh) {    // j = 4*hh .. 4*hh+3
        h4 na = ring4[k + 2 * hh + 1];   // points {2k+4hh+2, +3}
        h4 nb = ring4[k + 2 * hh + 2];   // points {2k+4hh+4, +5}
        h8 P0 = q0_8[hh];                // pred0 points {4hh..4hh+3}
        h8 P1 = q1_8[hh];

        h2 Wl = lo2(W), Wh = hi2(W), Al = lo2(na), Ah = hi2(na), Bl = lo2(nb);
        h2 p0a = __builtin_shufflevector(P0, P0, 0, 1);
        h2 p0b = __builtin_shufflevector(P0, P0, 2, 3);
        h2 p0c = __builtin_shufflevector(P0, P0, 4, 5);
        h2 p0d = __builtin_shufflevector(P0, P0, 6, 7);
        h2 p1a = __builtin_shufflevector(P1, P1, 0, 1);
        h2 p1b = __builtin_shufflevector(P1, P1, 2, 3);
        h2 p1c = __builtin_shufflevector(P1, P1, 4, 5);
        h2 p1d = __builtin_shufflevector(P1, P1, 6, 7);

        // pred0: shift 2k, then 2k+1
        unit(p0a, Wl, a00); unit(p0b, Wh, a00); unit(p0c, Al, a00); unit(p0d, Ah, a00);
        unit(p0a, Wh, a01); unit(p0b, Al, a01); unit(p0c, Ah, a01); unit(p0d, Bl, a01);
        // pred1
        unit(p1a, Wl, a10); unit(p1b, Wh, a10); unit(p1c, Al, a10); unit(p1d, Ah, a10);
        unit(p1a, Wh, a11); unit(p1b, Al, a11); unit(p1c, Ah, a11); unit(p1d, Bl, a11);

        W = nb;
    }

    // per-pred min over lane's 2 shifts, then over the wave
    float r0 = fminf(a00, a01);
    float r1 = fminf(a10, a11);
#pragma unroll
    for (int m = 32; m > 0; m >>= 1) {
        r0 = fminf(r0, __shfl_xor(r0, m, 64));
        r1 = fminf(r1, __shfl_xor(r1, m, 64));
    }

    __shared__ float bsum[WPB];
    if (k == 0) bsum[w] = r0 + r1;
    __syncthreads();
    if (t == 0) {
        float blockpart = bsum[0] + bsum[1] + bsum[2] + bsum[3];
        // relaxed device-scope atomic; NO fence (R5 lesson: fences -> L2 writeback storm)
        atomicAdd(out, blockpart * (1.0f / (2.0f * BATCH * PNUM)));
    }
}

extern "C" void kernel_launch(void* const* d_in, const int* in_sizes, int n_in,
                              void* d_out, int out_size, void* d_ws, size_t ws_size,
                              hipStream_t stream) {
    const float* pred0 = (const float*)d_in[0];
    const float* pred1 = (const float*)d_in[1];
    const float* gt    = (const float*)d_in[2];
    float* out = (float*)d_out;

    (void)hipMemsetAsync(out, 0, sizeof(float), stream);   // out is 0xAA-poisoned
    match_fused<<<GRID1, 64 * WPB, 0, stream>>>(pred0, pred1, gt, out);
}